// Round 3
// baseline (411.022 us; speedup 1.0000x reference)
//
#include <hip/hip_runtime.h>

namespace {

constexpr float SCALE = 0.35355339059327373f;  // (1/sqrt(2))^3

typedef float fvec4 __attribute__((ext_vector_type(4)));  // nontemporal-OK vec

// x: (1024 rows, 65536) -> out: (1024 rows, 8 bands, 8192), Gray-code band order.
//
// Each thread loads 8 CONSECUTIVE floats (one complete 8-group) -> computes all
// 8 band values lane-locally (zero shuffles) -> stages into an 8KB LDS tile
// [band][256 cols]. After one barrier, each wave reads back contiguous band
// rows (dense ds_read_b128) and stores 1KB-contiguous segments per band:
// wave w stores band w (cols 0..255 of the block tile) then band w+4.
// This replaces the previous wave-store pattern of 8 scattered 128B segments
// (32KB apart) with single 1KB contiguous segments per store instruction.
//
// Natural band n (bits = level1,level2,level3 a=0/d=1) -> Gray slot k:
//   n: 0 1 2 3 4 5 6 7  ->  k: 0 1 3 2 7 6 4 5
__global__ __launch_bounds__(256) void wpt3_kernel(const float* __restrict__ x,
                                                   float* __restrict__ out) {
    __shared__ __align__(16) float lds[8][256];

    const int t = (int)threadIdx.x;
    const long long b = blockIdx.x;  // block handles 2048 floats = 256 groups

    // Loads: thread t takes float4 #(2t) and #(2t+1) of the block's 512.
    const fvec4* in4 = reinterpret_cast<const fvec4*>(x) + (b << 9);
    const fvec4 va = __builtin_nontemporal_load(in4 + 2 * t);
    const fvec4 vb = __builtin_nontemporal_load(in4 + 2 * t + 1);

    // Level 1: 4 pairs.
    const float s0 = va.x + va.y, t0 = va.x - va.y;
    const float s1 = va.z + va.w, t1 = va.z - va.w;
    const float s2 = vb.x + vb.y, t2 = vb.x - vb.y;
    const float s3 = vb.z + vb.w, t3 = vb.z - vb.w;
    // Level 2.
    const float aa0 = s0 + s1, ad0 = s0 - s1, da0 = t0 + t1, dd0 = t0 - t1;
    const float aa1 = s2 + s3, ad1 = s2 - s3, da1 = t2 + t3, dd1 = t2 - t3;
    // Level 3 (natural order n0..n7).
    const float n0 = aa0 + aa1;  // aaa
    const float n1 = aa0 - aa1;  // aad
    const float n2 = ad0 + ad1;  // ada
    const float n3 = ad0 - ad1;  // add
    const float n4 = da0 + da1;  // daa
    const float n5 = da0 - da1;  // dad
    const float n6 = dd0 + dd1;  // dda
    const float n7 = dd0 - dd1;  // ddd

    // Gray-slot placement. Bank = t%32 for every write: 2 lanes/bank = free.
    lds[0][t] = n0 * SCALE;
    lds[1][t] = n1 * SCALE;
    lds[2][t] = n3 * SCALE;
    lds[3][t] = n2 * SCALE;
    lds[4][t] = n6 * SCALE;
    lds[5][t] = n7 * SCALE;
    lds[6][t] = n5 * SCALE;
    lds[7][t] = n4 * SCALE;

    __syncthreads();

    // Store: wave w (=t>>6) handles bands w and w+4; lane = c4 = t&63 picks
    // the float4 chunk -> per store instruction: 64 lanes x 16B = 1KB dense.
    const int c4 = t & 63;
    const int band0 = t >> 6;  // 0..3
    const int row = (int)(b >> 5);            // 32 blocks per input row
    const int colbase = ((int)b & 31) << 8;   // 256 cols per block tile

    const fvec4* l4 = reinterpret_cast<const fvec4*>(&lds[0][0]);
    float* obase = out + (long long)row * 65536 + colbase + (c4 << 2);

    const fvec4 r0 = l4[band0 * 64 + c4];
    __builtin_nontemporal_store(
        r0, reinterpret_cast<fvec4*>(obase + (long long)band0 * 8192));
    const fvec4 r1 = l4[(band0 + 4) * 64 + c4];
    __builtin_nontemporal_store(
        r1, reinterpret_cast<fvec4*>(obase + (long long)(band0 + 4) * 8192));
}

}  // namespace

extern "C" void kernel_launch(void* const* d_in, const int* in_sizes, int n_in,
                              void* d_out, int out_size, void* d_ws, size_t ws_size,
                              hipStream_t stream) {
    const float* x = (const float*)d_in[0];
    float* out = (float*)d_out;
    // 67,108,864 floats / 2048 per block = 32768 blocks.
    dim3 grid(32768), block(256);
    hipLaunchKernelGGL(wpt3_kernel, grid, block, 0, stream, x, out);
}

// Round 4
// 405.065 us; speedup vs baseline: 1.0147x; 1.0147x over previous
//
#include <hip/hip_runtime.h>

namespace {

constexpr float SCALE = 0.35355339059327373f;  // (1/sqrt(2))^3

typedef float fvec4 __attribute__((ext_vector_type(4)));  // nontemporal-OK vec

// x: (1024 rows, 65536) -> out: (1024 rows, 8 bands, 8192), Gray-code band order.
// Every 8 consecutive inputs produce one column in each of the 8 bands.
//
// FINAL (best-measured) variant, 405.8 us total in R2. Roofline analysis:
// kernel's mandatory HBM traffic = 268 MB read + 268 MB write = 537 MB
// ~= 85-95 us at the ~6.3 TB/s achievable ceiling (the harness's own 1.07 GB
// fill sustains 6.4-6.6 TB/s). Write-side restructurings (scalar->dense
// float4 in R2, 1KB-contiguous LDS staging in R3) both landed within the
// +-1% noise band => kernel is at the memory floor; residual dur_us is
// harness re-poison + restore, not kernel time.
//
// Stage 0 (lane-local): float4 = 2 level-1 pairs -> level-2 {aa,ad,da,dd} halves.
// Stage 1 (shfl_xor 1): combine with neighbor lane -> each lane holds 4 band
//          values for ONE column: even lane slots {0,3,4,7}, odd {1,2,5,6}.
// Stage 2+3 (shfl_xor 4, shfl_xor 2): 4x4 register transpose across the four
//          same-parity lanes of each octet -> each lane holds ONE band slot for
//          FOUR consecutive columns -> single aligned 16B store per thread.
// Per wave: 8 bands x 128B fully-dense contiguous segments in ONE store instr.
__global__ __launch_bounds__(256) void wpt3_kernel(const float* __restrict__ x,
                                                   float* __restrict__ out) {
    const long long tid = (long long)blockIdx.x * 256 + threadIdx.x;
    const int lane_odd = (int)(tid & 1);

    // Coalesced, touch-once: nontemporal 16B load.
    const fvec4 v =
        __builtin_nontemporal_load(reinterpret_cast<const fvec4*>(x) + tid);

    // Level 1 (lane-local): 2 pairs.
    const float s0 = v.x + v.y, t0 = v.x - v.y;
    const float s1 = v.z + v.w, t1 = v.z - v.w;
    // Level 2 (lane-local): this lane holds half-group {aa,ad,da,dd}.
    const float p = s0 + s1;  // aa half
    const float q = s0 - s1;  // ad half
    const float r = t0 + t1;  // da half
    const float u = t0 - t1;  // dd half

    // Stage 1: level 3 via neighbor lane (other half of the 8-group).
    const float pp = __shfl_xor(p, 1, 64);
    const float qq = __shfl_xor(q, 1, 64);
    const float rr = __shfl_xor(r, 1, 64);
    const float uu = __shfl_xor(u, 1, 64);

    // Even lane: sum bands; odd lane: diff bands (slot^1).
    // Register i -> slot: even (0,3,4,7)[i], odd (1,2,5,6)[i].
    float b0 = (lane_odd ? (pp - p) : (p + pp)) * SCALE;  // slot 0 / 1
    float b1 = (lane_odd ? (qq - q) : (q + qq)) * SCALE;  // slot 3 / 2
    float b2 = (lane_odd ? (uu - u) : (u + uu)) * SCALE;  // slot 4 / 5
    float b3 = (lane_odd ? (rr - r) : (r + rr)) * SCALE;  // slot 7 / 6

    // 4x4 transpose across same-parity lanes of the octet.
    // j = position within the parity set = (lane>>1)&3; j bit1 -> lane xor 4,
    // j bit0 -> lane xor 2. Both stages preserve parity.
    const int lane = (int)(threadIdx.x & 63);
    const int jb1 = (lane >> 2) & 1;
    const int jb0 = (lane >> 1) & 1;

    // Stage 2 (xor 4): swap off-diagonal 2x2 blocks.
    {
        const float ta = jb1 ? b0 : b2;
        const float tb = jb1 ? b1 : b3;
        const float ra = __shfl_xor(ta, 4, 64);
        const float rb = __shfl_xor(tb, 4, 64);
        if (jb1 == 0) { b2 = ra; b3 = rb; } else { b0 = ra; b1 = rb; }
    }
    // Stage 3 (xor 2): transpose within each 2x2 block.
    {
        const float ta = jb0 ? b0 : b1;
        const float tb = jb0 ? b2 : b3;
        const float ra = __shfl_xor(ta, 2, 64);
        const float rb = __shfl_xor(tb, 2, 64);
        if (jb0 == 0) { b1 = ra; b3 = rb; } else { b0 = ra; b2 = rb; }
    }

    // Now lane (parity, j) holds band slot(j,parity) for cols [4*octet .. +4).
    // slot = 2*j + ((j&1) ^ parity):
    //   even: j=0..3 -> 0,3,4,7 ; odd: j=0..3 -> 1,2,5,6.
    const int j = (lane >> 1) & 3;
    const int slot = (j << 1) + ((j & 1) ^ lane_odd);

    const long long octet = tid >> 3;           // 4 groups (=cols) per octet
    const long long gbase = octet << 2;         // first col (global group idx)
    const int row = (int)(gbase >> 13);         // 8192 cols per row
    const int col = (int)(gbase & 8191);        // multiple of 4 -> 16B aligned

    fvec4 o;
    o.x = b0; o.y = b1; o.z = b2; o.w = b3;     // cols col..col+3 of `slot`
    fvec4* op = reinterpret_cast<fvec4*>(out + (long long)row * 65536 +
                                         (long long)slot * 8192 + col);
    __builtin_nontemporal_store(o, op);
}

}  // namespace

extern "C" void kernel_launch(void* const* d_in, const int* in_sizes, int n_in,
                              void* d_out, int out_size, void* d_ws, size_t ws_size,
                              hipStream_t stream) {
    const float* x = (const float*)d_in[0];
    float* out = (float*)d_out;
    // 67,108,864 floats / 4 per thread = 16,777,216 threads.
    dim3 grid(65536), block(256);
    hipLaunchKernelGGL(wpt3_kernel, grid, block, 0, stream, x, out);
}